// Round 2
// baseline (454.608 us; speedup 1.0000x reference)
//
#include <hip/hip_runtime.h>
#include <cstdint>

// FlowProjectionModule: forward-warp flow splatting + count-normalize + hole fill.
// B=16, C=2, H=720, W=1280, fp32 in/out.
//
// R1: fill_k was 118us (26% of wall) at 11% HBM -> latency-bound on serial
// UP/DOWN mask walks (dependent 8B loads at 160B stride, up to 720 iters).
// Add a bit-transposed column mask (12 u64/column, 2MB) built by an
// in-register 64x64 bit transpose; vertical nearest-valid becomes the same
// clz/ffs contiguous word scan as horizontal. Splat path unchanged.

static constexpr int Bn = 16;
static constexpr int Hn = 720;
static constexpr int Wn = 1280;
static constexpr int HW = Hn * Wn;
static constexpr long long TOT = (long long)Bn * HW;    // 14,745,600
static constexpr int HB = 8;                            // images per chunk
static constexpr int CH_TOT = HB * HW;                  // 7,372,800
static constexpr int NBINC = HB * Hn;                   // 5760 bins (b_local, yT)

static constexpr int RG   = 8;               // source rows per binning block
static constexpr int HALO = 64;              // |fy|<=64 via LDS hist; else global fallback
static constexpr int NH   = RG + 2 * HALO;   // 136 local bins
static constexpr int NW   = 16;              // waves per 1024-thread block

static constexpr int S  = 4;                 // target rows per accum strip
static constexpr int SW = S * Wn;            // 5120 cells

static constexpr int CW  = 12;               // u64 words per column mask (768 bits >= 720)
static constexpr int WPR = Wn / 64;          // 20 row-mask words per row

// ---------------- Pass A1: per-bin counts (per-wave sub-histograms) ----------------
__global__ __launch_bounds__(1024) void count_k(const float* __restrict__ flow,
                                                int* __restrict__ bin_count) {
    __shared__ int hist[NW][NH];             // 8704 B
    int bl = blockIdx.x / (Hn / RG);
    int g  = blockIdx.x % (Hn / RG);
    int y0 = g * RG;
    int wv = threadIdx.x >> 6;
    for (int i = threadIdx.x; i < NW * NH; i += 1024) ((int*)hist)[i] = 0;
    __syncthreads();

    const float* f = flow + (size_t)bl * 2 * HW;
    #pragma unroll
    for (int k = 0; k < 10; ++k) {
        int i  = threadIdx.x + k * 1024;     // RG*Wn = 10240 exactly
        int ry = i / Wn;
        int x  = i - ry * Wn;
        int y  = y0 + ry;
        int p  = y * Wn + x;
        float fx = f[p];
        float fy = f[p + HW];
        float x2 = (float)x + fx;
        float y2 = (float)y + fy;
        if (!(x2 >= 0.f && y2 >= 0.f && x2 <= (float)(Wn - 1) && y2 <= (float)(Hn - 1)))
            continue;
        int yT  = (int)floorf(y2);
        int rel = yT - y0 + HALO;
        if (rel >= 0 && rel < NH) atomicAdd(&hist[wv][rel], 1);
        else                      atomicAdd(&bin_count[bl * Hn + yT], 1);   // outlier
    }
    __syncthreads();
    for (int i = threadIdx.x; i < NH; i += 1024) {
        int tot = 0;
        for (int w = 0; w < NW; ++w) tot += hist[w][i];
        int row = y0 - HALO + i;
        if (tot > 0 && row >= 0 && row < Hn)
            atomicAdd(&bin_count[bl * Hn + row], tot);
    }
}

// ---------------- Pass A2: exclusive scan of 5760 bins (single block) ----------------
__global__ __launch_bounds__(1024) void scan_k(const int* __restrict__ bin_count,
                                               int* __restrict__ off,
                                               int* __restrict__ cur) {
    __shared__ int s[1024];
    const int PER = (NBINC + 1023) / 1024;   // 6
    int t  = threadIdx.x;
    int lo = t * PER;
    int local[PER];
    int sum = 0;
    for (int k = 0; k < PER; ++k) {
        int i = lo + k;
        int v = (i < NBINC) ? bin_count[i] : 0;
        local[k] = v;
        sum += v;
    }
    s[t] = sum;
    __syncthreads();
    for (int d = 1; d < 1024; d <<= 1) {
        int v = (t >= d) ? s[t - d] : 0;
        __syncthreads();
        s[t] += v;
        __syncthreads();
    }
    int base = s[t] - sum;
    for (int k = 0; k < PER; ++k) {
        int i = lo + k;
        if (i < NBINC) {
            off[i] = base;
            cur[i] = base;
            base += local[k];
        }
    }
    if (t == 1023) off[NBINC] = s[1023];
}

// ---------------- Pass A3: emit packed u64 records into bin segments ----------------
// record: [fyq_b:19 @41][fxq_b:19 @22][yT:11 @11][xL:11 @0], q = round(-f*128)+2^18
__global__ __launch_bounds__(1024) void emit_k(const float* __restrict__ flow,
                                               int* __restrict__ cur,
                                               unsigned long long* __restrict__ recs) {
    __shared__ int hist[NW][NH];             // counts, then absolute per-wave cursors
    int bl = blockIdx.x / (Hn / RG);
    int g  = blockIdx.x % (Hn / RG);
    int y0 = g * RG;
    int wv = threadIdx.x >> 6;
    for (int i = threadIdx.x; i < NW * NH; i += 1024) ((int*)hist)[i] = 0;
    __syncthreads();

    const float* f = flow + (size_t)bl * 2 * HW;
    float cfx[10], cfy[10];
    #pragma unroll
    for (int k = 0; k < 10; ++k) {
        int i  = threadIdx.x + k * 1024;
        int ry = i / Wn;
        int x  = i - ry * Wn;
        int y  = y0 + ry;
        int p  = y * Wn + x;
        float fx = f[p];
        float fy = f[p + HW];
        cfx[k] = fx;
        cfy[k] = fy;
        float x2 = (float)x + fx;
        float y2 = (float)y + fy;
        if (!(x2 >= 0.f && y2 >= 0.f && x2 <= (float)(Wn - 1) && y2 <= (float)(Hn - 1)))
            continue;
        int yT  = (int)floorf(y2);
        int rel = yT - y0 + HALO;
        if (rel >= 0 && rel < NH) atomicAdd(&hist[wv][rel], 1);
    }
    __syncthreads();
    for (int i = threadIdx.x; i < NH; i += 1024) {
        int tot = 0;
        for (int w = 0; w < NW; ++w) tot += hist[w][i];
        int row = y0 - HALO + i;
        int run = 0;
        if (tot > 0 && row >= 0 && row < Hn)
            run = atomicAdd(&cur[bl * Hn + row], tot);
        for (int w = 0; w < NW; ++w) {
            int c = hist[w][i];
            hist[w][i] = run;
            run += c;
        }
    }
    __syncthreads();
    #pragma unroll
    for (int k = 0; k < 10; ++k) {
        int i  = threadIdx.x + k * 1024;
        int ry = i / Wn;
        int x  = i - ry * Wn;
        int y  = y0 + ry;
        float fx = cfx[k];
        float fy = cfy[k];
        float x2 = (float)x + fx;
        float y2 = (float)y + fy;
        if (!(x2 >= 0.f && y2 >= 0.f && x2 <= (float)(Wn - 1) && y2 <= (float)(Hn - 1)))
            continue;
        int xL = (int)floorf(x2); xL = max(0, min(xL, Wn - 1));
        int yT = (int)floorf(y2);
        int fxq = __float2int_rn(-fx * 128.f) + (1 << 18);   // in (0, 2^19)
        int fyq = __float2int_rn(-fy * 128.f) + (1 << 18);
        unsigned long long rec = (unsigned long long)(unsigned)xL
                               | ((unsigned long long)(unsigned)yT  << 11)
                               | ((unsigned long long)(unsigned)fxq << 22)
                               | ((unsigned long long)(unsigned)fyq << 41);
        int rel = yT - y0 + HALO;
        int slot;
        if (rel >= 0 && rel < NH) slot = atomicAdd(&hist[wv][rel], 1);
        else                      slot = atomicAdd(&cur[bl * Hn + yT], 1);   // outlier
        recs[slot] = rec;
    }
}

// ---------------- Pass B: strip u64-packed LDS accumulation + fused normalize ----------------
__global__ __launch_bounds__(512, 8) void accum_k(const int* __restrict__ off,
                                                  const unsigned long long* __restrict__ recs,
                                                  float* __restrict__ out,
                                                  unsigned long long* __restrict__ mask) {
    __shared__ unsigned long long accQ[SW];  // 40 KB: [fy:27][fx:27][cnt:10] per cell
    int bl = blockIdx.x / (Hn / S);
    int st = blockIdx.x % (Hn / S);
    int r0 = st * S;

    for (int i = threadIdx.x; i < SW; i += 512) accQ[i] = 0ull;
    __syncthreads();

    int rlo = max(r0 - 1, 0);
    int rhi = r0 + S - 1;
    int lo  = off[bl * Hn + rlo];
    int hi  = off[bl * Hn + rhi + 1];

    for (int j = lo + threadIdx.x; j < hi; j += 512) {
        unsigned long long rec = recs[j];
        int xL = (int)(rec & 0x7FFu);
        int yT = (int)((rec >> 11) & 0x7FFu);
        unsigned long long t = (((rec >> 41) & 0x7FFFFull) << 37)
                             | (((rec >> 22) & 0x7FFFFull) << 10) | 1ull;
        int xR = min(xL + 1, Wn - 1);
        int yB = min(yT + 1, Hn - 1);
        #pragma unroll
        for (int rr = 0; rr < 2; ++rr) {
            int row = rr ? yB : yT;          // yT==yB at bottom edge -> double add (matches ref)
            if (row >= r0 && row < r0 + S) {
                int rb = (row - r0) * Wn;
                atomicAdd(&accQ[rb + xL], t);
                atomicAdd(&accQ[rb + xR], t);   // xL==xR at right edge -> double add
            }
        }
    }
    __syncthreads();

    float* ox = out + (size_t)bl * 2 * HW;
    size_t pixbase = (size_t)bl * HW + (size_t)r0 * Wn;  // multiple of 64
    for (int i = threadIdx.x; i < SW; i += 512) {        // 10 iters, all lanes active
        int rw  = i / Wn;
        int col = i - rw * Wn;
        int p   = (r0 + rw) * Wn + col;
        unsigned long long v = accQ[i];
        unsigned c = (unsigned)(v & 1023ull);
        float vx = 0.f, vy = 0.f;
        if (c) {
            int sfx = (int)((v >> 10) & 0x7FFFFFFull) - (int)(c << 18);
            int sfy = (int)((v >> 37) & 0x7FFFFFFull) - (int)(c << 18);
            float inv = 1.f / (128.f * (float)c);
            vx = (float)sfx * inv;
            vy = (float)sfy * inv;
        }
        ox[p]      = vx;
        ox[p + HW] = vy;
        unsigned long long m = __ballot(c != 0);
        if ((threadIdx.x & 63) == 0) mask[(pixbase + (size_t)i) >> 6] = m;
    }
}

// ---------------- bit-transpose row mask -> column mask ----------------
// colmask[(b*Wn + x)*CW + w] bit j = mask bit for (b, row w*64+j, col x).
// In-register 64x64 bit transpose per wave (Hacker's Delight butterfly).
__global__ __launch_bounds__(256) void transpose_k(const unsigned long long* __restrict__ mask,
                                                   unsigned long long* __restrict__ colmask) {
    int tile = blockIdx.x * 4 + (threadIdx.x >> 6);   // (b, tY, xw)
    int lane = threadIdx.x & 63;
    int xw = tile % WPR;
    int tY = (tile / WPR) % CW;
    int b  = tile / (WPR * CW);
    int y  = tY * 64 + lane;

    unsigned long long x = 0ull;
    if (y < Hn) x = mask[(size_t)b * (HW / 64) + (size_t)y * WPR + xw];
    x = __builtin_bitreverse64(x);           // MSB-first convention for HD transpose

    unsigned long long m = 0x00000000FFFFFFFFull;
    #pragma unroll
    for (int j = 32; j != 0; j >>= 1, m ^= (m << j)) {
        unsigned long long p = __shfl_xor(x, j);
        bool hi = (lane & j) != 0;
        unsigned long long lo_w = hi ? p : x;
        unsigned long long hi_w = hi ? x : p;
        unsigned long long t = (lo_w ^ (hi_w >> j)) & m;
        x ^= hi ? (t << j) : t;
    }
    x = __builtin_bitreverse64(x);           // back to LSB = smallest row

    int col = xw * 64 + lane;
    colmask[((size_t)b * Wn + col) * CW + tY] = x;
}

// ---------------- hole fill via bitmask (row + column masks) ----------------
__global__ __launch_bounds__(256) void fill_k(float* __restrict__ out,
                                              const unsigned long long* __restrict__ mask,
                                              const unsigned long long* __restrict__ colmask) {
    long long t = (long long)blockIdx.x * blockDim.x + threadIdx.x;
    if (t >= TOT) return;
    int b = (int)(t / HW);
    int p = (int)(t - (long long)b * HW);
    int y = p / Wn;
    int x = p - y * Wn;

    size_t bbase = (size_t)b * HW;
    int bit = x & 63;
    if ((mask[(bbase + (size_t)p) >> 6] >> bit) & 1) return;   // not a hole

    float* ox = out + (size_t)b * 2 * HW;
    const unsigned long long* rowmask = mask + ((bbase + (size_t)y * Wn) >> 6);  // 20 words/row
    const unsigned long long* cm = colmask + ((size_t)b * Wn + x) * CW;          // 12 words/col
    float sx = 0.f, sy = 0.f, num = 0.f;

    // nearest valid LEFT
    {
        int w = x >> 6;
        unsigned long long m = bit ? (rowmask[w] & ((1ull << bit) - 1)) : 0ull;
        int lx = -1;
        while (true) {
            if (m) { lx = (w << 6) + 63 - __clzll(m); break; }
            if (--w < 0) break;
            m = rowmask[w];
        }
        if (lx >= 0) { int q = y * Wn + lx; sx += ox[q]; sy += ox[q + HW]; num += 1.f; }
    }
    // nearest valid RIGHT
    {
        int w = x >> 6;
        unsigned long long m = rowmask[w] & ~((2ull << bit) - 1);   // bits > bit (bit=63 -> 0)
        int rx = -1;
        while (true) {
            if (m) { rx = (w << 6) + __ffsll((long long)m) - 1; break; }
            if (++w >= WPR) break;
            m = rowmask[w];
        }
        if (rx >= 0) { int q = y * Wn + rx; sx += ox[q]; sy += ox[q + HW]; num += 1.f; }
    }
    // nearest valid UP (largest row < y with bit set)
    {
        int wq = y >> 6, rb = y & 63;
        unsigned long long m = rb ? (cm[wq] & ((1ull << rb) - 1)) : 0ull;
        int uy = -1, w = wq;
        while (true) {
            if (m) { uy = (w << 6) + 63 - __clzll(m); break; }
            if (--w < 0) break;
            m = cm[w];
        }
        if (uy >= 0) { int q = uy * Wn + x; sx += ox[q]; sy += ox[q + HW]; num += 1.f; }
    }
    // nearest valid DOWN (smallest row > y; bits >= Hn are always 0)
    {
        int wq = y >> 6, rb = y & 63;
        unsigned long long m = cm[wq] & ~((2ull << rb) - 1);
        int dy = -1, w = wq;
        while (true) {
            if (m) { dy = (w << 6) + __ffsll((long long)m) - 1; break; }
            if (++w >= CW) break;
            m = cm[w];
        }
        if (dy >= 0) { int q = dy * Wn + x; sx += ox[q]; sy += ox[q + HW]; num += 1.f; }
    }

    if (num > 0.f) {
        ox[p]      = sx / num;
        ox[p + HW] = sy / num;
    }
}

extern "C" void kernel_launch(void* const* d_in, const int* in_sizes, int n_in,
                              void* d_out, int out_size, void* d_ws, size_t ws_size,
                              hipStream_t stream) {
    const float* flow = (const float*)d_in[0];
    float* out = (float*)d_out;

    // workspace (~63 MB):
    char* ws = (char*)d_ws;
    size_t o = 0;
    unsigned long long* recs = (unsigned long long*)(ws + o);
    o += (size_t)CH_TOT * 8;                                       // 59.0 MB
    unsigned long long* mask = (unsigned long long*)(ws + o);
    o += (size_t)(TOT / 64) * 8;                                   // 1.84 MB
    unsigned long long* colmask = (unsigned long long*)(ws + o);
    o += (size_t)Bn * Wn * CW * 8;                                 // 1.97 MB
    o = (o + 255) & ~(size_t)255;
    int* bin_count = (int*)(ws + o); o += (size_t)NBINC * 4;
    o = (o + 255) & ~(size_t)255;
    int* off = (int*)(ws + o);       o += (size_t)(NBINC + 1) * 4;
    o = (o + 255) & ~(size_t)255;
    int* cur = (int*)(ws + o);       o += (size_t)NBINC * 4;

    const int bin_blocks   = HB * (Hn / RG);   // 720
    const int strip_blocks = HB * (Hn / S);    // 1440

    for (int chunk = 0; chunk < 2; ++chunk) {
        const float* fchunk = flow + (size_t)chunk * HB * 2 * HW;
        float* ochunk = out + (size_t)chunk * HB * 2 * HW;
        unsigned long long* mchunk = mask + (size_t)chunk * (HB * HW / 64);

        hipMemsetAsync(bin_count, 0, (size_t)NBINC * 4, stream);
        count_k<<<bin_blocks, 1024, 0, stream>>>(fchunk, bin_count);
        scan_k<<<1, 1024, 0, stream>>>(bin_count, off, cur);
        emit_k<<<bin_blocks, 1024, 0, stream>>>(fchunk, cur, recs);
        accum_k<<<strip_blocks, 512, 0, stream>>>(off, recs, ochunk, mchunk);
    }

    const int tr_tiles  = Bn * CW * WPR;               // 3840 tiles
    transpose_k<<<tr_tiles / 4, 256, 0, stream>>>(mask, colmask);

    const int threads = 256;
    const int blocks = (int)((TOT + threads - 1) / threads);   // 57600
    fill_k<<<blocks, threads, 0, stream>>>(out, mask, colmask);
}

// Round 3
// 442.964 us; speedup vs baseline: 1.0263x; 1.0263x over previous
//
#include <hip/hip_runtime.h>
#include <cstdint>

// FlowProjectionModule: forward-warp flow splatting + count-normalize + hole fill.
// B=16, C=2, H=720, W=1280, fp32 in/out.
//
// R2: fill_k was 109us = 92MB FETCH at 1.0 TB/s -> latency-bound hole gathers
// (98% of threads exit; surviving waves carry 1-2 holes, serial line-misses).
// Fix: compact holes into a dense u32 list (reuses dead recs buffer), then
// fill with 64 holes/wave -> gathers issue 64-wide, MLP restored.
// Splat path (count/scan/emit/accum) unchanged.

static constexpr int Bn = 16;
static constexpr int Hn = 720;
static constexpr int Wn = 1280;
static constexpr int HW = Hn * Wn;
static constexpr long long TOT = (long long)Bn * HW;    // 14,745,600
static constexpr int HB = 8;                            // images per chunk
static constexpr int CH_TOT = HB * HW;                  // 7,372,800
static constexpr int NBINC = HB * Hn;                   // 5760 bins (b_local, yT)

static constexpr int RG   = 8;               // source rows per binning block
static constexpr int HALO = 64;              // |fy|<=64 via LDS hist; else global fallback
static constexpr int NH   = RG + 2 * HALO;   // 136 local bins
static constexpr int NW   = 16;              // waves per 1024-thread block

static constexpr int S  = 4;                 // target rows per accum strip
static constexpr int SW = S * Wn;            // 5120 cells

static constexpr int CW  = 12;               // u64 words per column mask (768 bits >= 720)
static constexpr int WPR = Wn / 64;          // 20 row-mask words per row
static constexpr int NWORDS = (int)(TOT / 64);           // 230,400 mask words

// ---------------- Pass A1: per-bin counts (per-wave sub-histograms) ----------------
__global__ __launch_bounds__(1024) void count_k(const float* __restrict__ flow,
                                                int* __restrict__ bin_count) {
    __shared__ int hist[NW][NH];             // 8704 B
    int bl = blockIdx.x / (Hn / RG);
    int g  = blockIdx.x % (Hn / RG);
    int y0 = g * RG;
    int wv = threadIdx.x >> 6;
    for (int i = threadIdx.x; i < NW * NH; i += 1024) ((int*)hist)[i] = 0;
    __syncthreads();

    const float* f = flow + (size_t)bl * 2 * HW;
    #pragma unroll
    for (int k = 0; k < 10; ++k) {
        int i  = threadIdx.x + k * 1024;     // RG*Wn = 10240 exactly
        int ry = i / Wn;
        int x  = i - ry * Wn;
        int y  = y0 + ry;
        int p  = y * Wn + x;
        float fx = f[p];
        float fy = f[p + HW];
        float x2 = (float)x + fx;
        float y2 = (float)y + fy;
        if (!(x2 >= 0.f && y2 >= 0.f && x2 <= (float)(Wn - 1) && y2 <= (float)(Hn - 1)))
            continue;
        int yT  = (int)floorf(y2);
        int rel = yT - y0 + HALO;
        if (rel >= 0 && rel < NH) atomicAdd(&hist[wv][rel], 1);
        else                      atomicAdd(&bin_count[bl * Hn + yT], 1);   // outlier
    }
    __syncthreads();
    for (int i = threadIdx.x; i < NH; i += 1024) {
        int tot = 0;
        for (int w = 0; w < NW; ++w) tot += hist[w][i];
        int row = y0 - HALO + i;
        if (tot > 0 && row >= 0 && row < Hn)
            atomicAdd(&bin_count[bl * Hn + row], tot);
    }
}

// ---------------- Pass A2: exclusive scan of 5760 bins (single block) ----------------
__global__ __launch_bounds__(1024) void scan_k(const int* __restrict__ bin_count,
                                               int* __restrict__ off,
                                               int* __restrict__ cur) {
    __shared__ int s[1024];
    const int PER = (NBINC + 1023) / 1024;   // 6
    int t  = threadIdx.x;
    int lo = t * PER;
    int local[PER];
    int sum = 0;
    for (int k = 0; k < PER; ++k) {
        int i = lo + k;
        int v = (i < NBINC) ? bin_count[i] : 0;
        local[k] = v;
        sum += v;
    }
    s[t] = sum;
    __syncthreads();
    for (int d = 1; d < 1024; d <<= 1) {
        int v = (t >= d) ? s[t - d] : 0;
        __syncthreads();
        s[t] += v;
        __syncthreads();
    }
    int base = s[t] - sum;
    for (int k = 0; k < PER; ++k) {
        int i = lo + k;
        if (i < NBINC) {
            off[i] = base;
            cur[i] = base;
            base += local[k];
        }
    }
    if (t == 1023) off[NBINC] = s[1023];
}

// ---------------- Pass A3: emit packed u64 records into bin segments ----------------
// record: [fyq_b:19 @41][fxq_b:19 @22][yT:11 @11][xL:11 @0], q = round(-f*128)+2^18
__global__ __launch_bounds__(1024) void emit_k(const float* __restrict__ flow,
                                               int* __restrict__ cur,
                                               unsigned long long* __restrict__ recs) {
    __shared__ int hist[NW][NH];             // counts, then absolute per-wave cursors
    int bl = blockIdx.x / (Hn / RG);
    int g  = blockIdx.x % (Hn / RG);
    int y0 = g * RG;
    int wv = threadIdx.x >> 6;
    for (int i = threadIdx.x; i < NW * NH; i += 1024) ((int*)hist)[i] = 0;
    __syncthreads();

    const float* f = flow + (size_t)bl * 2 * HW;
    float cfx[10], cfy[10];
    #pragma unroll
    for (int k = 0; k < 10; ++k) {
        int i  = threadIdx.x + k * 1024;
        int ry = i / Wn;
        int x  = i - ry * Wn;
        int y  = y0 + ry;
        int p  = y * Wn + x;
        float fx = f[p];
        float fy = f[p + HW];
        cfx[k] = fx;
        cfy[k] = fy;
        float x2 = (float)x + fx;
        float y2 = (float)y + fy;
        if (!(x2 >= 0.f && y2 >= 0.f && x2 <= (float)(Wn - 1) && y2 <= (float)(Hn - 1)))
            continue;
        int yT  = (int)floorf(y2);
        int rel = yT - y0 + HALO;
        if (rel >= 0 && rel < NH) atomicAdd(&hist[wv][rel], 1);
    }
    __syncthreads();
    for (int i = threadIdx.x; i < NH; i += 1024) {
        int tot = 0;
        for (int w = 0; w < NW; ++w) tot += hist[w][i];
        int row = y0 - HALO + i;
        int run = 0;
        if (tot > 0 && row >= 0 && row < Hn)
            run = atomicAdd(&cur[bl * Hn + row], tot);
        for (int w = 0; w < NW; ++w) {
            int c = hist[w][i];
            hist[w][i] = run;
            run += c;
        }
    }
    __syncthreads();
    #pragma unroll
    for (int k = 0; k < 10; ++k) {
        int i  = threadIdx.x + k * 1024;
        int ry = i / Wn;
        int x  = i - ry * Wn;
        int y  = y0 + ry;
        float fx = cfx[k];
        float fy = cfy[k];
        float x2 = (float)x + fx;
        float y2 = (float)y + fy;
        if (!(x2 >= 0.f && y2 >= 0.f && x2 <= (float)(Wn - 1) && y2 <= (float)(Hn - 1)))
            continue;
        int xL = (int)floorf(x2); xL = max(0, min(xL, Wn - 1));
        int yT = (int)floorf(y2);
        int fxq = __float2int_rn(-fx * 128.f) + (1 << 18);   // in (0, 2^19)
        int fyq = __float2int_rn(-fy * 128.f) + (1 << 18);
        unsigned long long rec = (unsigned long long)(unsigned)xL
                               | ((unsigned long long)(unsigned)yT  << 11)
                               | ((unsigned long long)(unsigned)fxq << 22)
                               | ((unsigned long long)(unsigned)fyq << 41);
        int rel = yT - y0 + HALO;
        int slot;
        if (rel >= 0 && rel < NH) slot = atomicAdd(&hist[wv][rel], 1);
        else                      slot = atomicAdd(&cur[bl * Hn + yT], 1);   // outlier
        recs[slot] = rec;
    }
}

// ---------------- Pass B: strip u64-packed LDS accumulation + fused normalize ----------------
__global__ __launch_bounds__(512, 8) void accum_k(const int* __restrict__ off,
                                                  const unsigned long long* __restrict__ recs,
                                                  float* __restrict__ out,
                                                  unsigned long long* __restrict__ mask) {
    __shared__ unsigned long long accQ[SW];  // 40 KB: [fy:27][fx:27][cnt:10] per cell
    int bl = blockIdx.x / (Hn / S);
    int st = blockIdx.x % (Hn / S);
    int r0 = st * S;

    for (int i = threadIdx.x; i < SW; i += 512) accQ[i] = 0ull;
    __syncthreads();

    int rlo = max(r0 - 1, 0);
    int rhi = r0 + S - 1;
    int lo  = off[bl * Hn + rlo];
    int hi  = off[bl * Hn + rhi + 1];

    for (int j = lo + threadIdx.x; j < hi; j += 512) {
        unsigned long long rec = recs[j];
        int xL = (int)(rec & 0x7FFu);
        int yT = (int)((rec >> 11) & 0x7FFu);
        unsigned long long t = (((rec >> 41) & 0x7FFFFull) << 37)
                             | (((rec >> 22) & 0x7FFFFull) << 10) | 1ull;
        int xR = min(xL + 1, Wn - 1);
        int yB = min(yT + 1, Hn - 1);
        #pragma unroll
        for (int rr = 0; rr < 2; ++rr) {
            int row = rr ? yB : yT;          // yT==yB at bottom edge -> double add (matches ref)
            if (row >= r0 && row < r0 + S) {
                int rb = (row - r0) * Wn;
                atomicAdd(&accQ[rb + xL], t);
                atomicAdd(&accQ[rb + xR], t);   // xL==xR at right edge -> double add
            }
        }
    }
    __syncthreads();

    float* ox = out + (size_t)bl * 2 * HW;
    size_t pixbase = (size_t)bl * HW + (size_t)r0 * Wn;  // multiple of 64
    for (int i = threadIdx.x; i < SW; i += 512) {        // 10 iters, all lanes active
        int rw  = i / Wn;
        int col = i - rw * Wn;
        int p   = (r0 + rw) * Wn + col;
        unsigned long long v = accQ[i];
        unsigned c = (unsigned)(v & 1023ull);
        float vx = 0.f, vy = 0.f;
        if (c) {
            int sfx = (int)((v >> 10) & 0x7FFFFFFull) - (int)(c << 18);
            int sfy = (int)((v >> 37) & 0x7FFFFFFull) - (int)(c << 18);
            float inv = 1.f / (128.f * (float)c);
            vx = (float)sfx * inv;
            vy = (float)sfy * inv;
        }
        ox[p]      = vx;
        ox[p + HW] = vy;
        unsigned long long m = __ballot(c != 0);
        if ((threadIdx.x & 63) == 0) mask[(pixbase + (size_t)i) >> 6] = m;
    }
}

// ---------------- bit-transpose row mask -> column mask ----------------
// colmask[(b*Wn + x)*CW + w] bit j = mask bit for (b, row w*64+j, col x).
// In-register 64x64 bit transpose per wave (Hacker's Delight butterfly).
__global__ __launch_bounds__(256) void transpose_k(const unsigned long long* __restrict__ mask,
                                                   unsigned long long* __restrict__ colmask) {
    int tile = blockIdx.x * 4 + (threadIdx.x >> 6);   // (b, tY, xw)
    int lane = threadIdx.x & 63;
    int xw = tile % WPR;
    int tY = (tile / WPR) % CW;
    int b  = tile / (WPR * CW);
    int y  = tY * 64 + lane;

    unsigned long long x = 0ull;
    if (y < Hn) x = mask[(size_t)b * (HW / 64) + (size_t)y * WPR + xw];
    x = __builtin_bitreverse64(x);           // MSB-first convention for HD transpose

    unsigned long long m = 0x00000000FFFFFFFFull;
    #pragma unroll
    for (int j = 32; j != 0; j >>= 1, m ^= (m << j)) {
        unsigned long long p = __shfl_xor(x, j);
        bool hi = (lane & j) != 0;
        unsigned long long lo_w = hi ? p : x;
        unsigned long long hi_w = hi ? x : p;
        unsigned long long t = (lo_w ^ (hi_w >> j)) & m;
        x ^= hi ? (t << j) : t;
    }
    x = __builtin_bitreverse64(x);           // back to LSB = smallest row

    int col = xw * 64 + lane;
    colmask[((size_t)b * Wn + col) * CW + tY] = x;
}

// ---------------- compact holes into a dense list ----------------
// One thread per mask word; wave-prefix + one atomic per wave.
__global__ __launch_bounds__(256) void compact_k(const unsigned long long* __restrict__ mask,
                                                 unsigned* __restrict__ holes,
                                                 unsigned* __restrict__ hole_cnt) {
    int w = blockIdx.x * 256 + threadIdx.x;          // grid sized exactly NWORDS
    int lane = threadIdx.x & 63;
    unsigned long long hb = ~mask[w];
    int cnt = __popcll(hb);
    int incl = cnt;
    #pragma unroll
    for (int d = 1; d < 64; d <<= 1) {
        int v = __shfl_up(incl, d);
        if (lane >= d) incl += v;
    }
    int total = __shfl(incl, 63);
    unsigned base = 0;
    if (total > 0) {
        if (lane == 63) base = atomicAdd(hole_cnt, (unsigned)total);
        base = (unsigned)__shfl((int)base, 63);
    }
    unsigned slot = base + (unsigned)(incl - cnt);
    unsigned gpb = (unsigned)w << 6;
    while (hb) {
        int b = __ffsll((long long)hb) - 1;
        holes[slot++] = gpb + (unsigned)b;
        hb &= hb - 1;
    }
}

// ---------------- hole fill over compacted list (all lanes = holes) ----------------
__global__ __launch_bounds__(256) void fillc_k(float* __restrict__ out,
                                               const unsigned long long* __restrict__ mask,
                                               const unsigned long long* __restrict__ colmask,
                                               const unsigned* __restrict__ holes,
                                               const unsigned* __restrict__ hole_cnt) {
    int n = (int)*hole_cnt;
    for (int i = blockIdx.x * 256 + threadIdx.x; i < n; i += gridDim.x * 256) {
        unsigned gp = holes[i];
        int b = (int)(gp / (unsigned)HW);
        int p = (int)(gp - (unsigned)b * (unsigned)HW);
        int y = p / Wn;
        int x = p - y * Wn;

        size_t bbase = (size_t)b * HW;
        int bit = x & 63;
        float* ox = out + (size_t)b * 2 * HW;
        const unsigned long long* rowmask = mask + ((bbase + (size_t)y * Wn) >> 6);
        const unsigned long long* cm = colmask + ((size_t)b * Wn + x) * CW;
        float sx = 0.f, sy = 0.f, num = 0.f;

        // nearest valid LEFT
        {
            int w = x >> 6;
            unsigned long long m = bit ? (rowmask[w] & ((1ull << bit) - 1)) : 0ull;
            int lx = -1;
            while (true) {
                if (m) { lx = (w << 6) + 63 - __clzll(m); break; }
                if (--w < 0) break;
                m = rowmask[w];
            }
            if (lx >= 0) { int q = y * Wn + lx; sx += ox[q]; sy += ox[q + HW]; num += 1.f; }
        }
        // nearest valid RIGHT
        {
            int w = x >> 6;
            unsigned long long m = rowmask[w] & ~((2ull << bit) - 1);   // bits > bit
            int rx = -1;
            while (true) {
                if (m) { rx = (w << 6) + __ffsll((long long)m) - 1; break; }
                if (++w >= WPR) break;
                m = rowmask[w];
            }
            if (rx >= 0) { int q = y * Wn + rx; sx += ox[q]; sy += ox[q + HW]; num += 1.f; }
        }
        // nearest valid UP (largest row < y)
        {
            int wq = y >> 6, rb = y & 63;
            unsigned long long m = rb ? (cm[wq] & ((1ull << rb) - 1)) : 0ull;
            int uy = -1, w = wq;
            while (true) {
                if (m) { uy = (w << 6) + 63 - __clzll(m); break; }
                if (--w < 0) break;
                m = cm[w];
            }
            if (uy >= 0) { int q = uy * Wn + x; sx += ox[q]; sy += ox[q + HW]; num += 1.f; }
        }
        // nearest valid DOWN (smallest row > y; bits >= Hn are 0)
        {
            int wq = y >> 6, rb = y & 63;
            unsigned long long m = cm[wq] & ~((2ull << rb) - 1);
            int dy = -1, w = wq;
            while (true) {
                if (m) { dy = (w << 6) + __ffsll((long long)m) - 1; break; }
                if (++w >= CW) break;
                m = cm[w];
            }
            if (dy >= 0) { int q = dy * Wn + x; sx += ox[q]; sy += ox[q + HW]; num += 1.f; }
        }

        if (num > 0.f) {
            ox[p]      = sx / num;
            ox[p + HW] = sy / num;
        }
    }
}

extern "C" void kernel_launch(void* const* d_in, const int* in_sizes, int n_in,
                              void* d_out, int out_size, void* d_ws, size_t ws_size,
                              hipStream_t stream) {
    const float* flow = (const float*)d_in[0];
    float* out = (float*)d_out;

    // workspace (~63 MB):
    char* ws = (char*)d_ws;
    size_t o = 0;
    unsigned long long* recs = (unsigned long long*)(ws + o);
    o += (size_t)CH_TOT * 8;                                       // 59.0 MB
    unsigned long long* mask = (unsigned long long*)(ws + o);
    o += (size_t)(TOT / 64) * 8;                                   // 1.84 MB
    unsigned long long* colmask = (unsigned long long*)(ws + o);
    o += (size_t)Bn * Wn * CW * 8;                                 // 1.97 MB
    o = (o + 255) & ~(size_t)255;
    int* bin_count = (int*)(ws + o); o += (size_t)NBINC * 4;
    o = (o + 255) & ~(size_t)255;
    int* off = (int*)(ws + o);       o += (size_t)(NBINC + 1) * 4;
    o = (o + 255) & ~(size_t)255;
    int* cur = (int*)(ws + o);       o += (size_t)NBINC * 4;
    o = (o + 255) & ~(size_t)255;
    unsigned* hole_cnt = (unsigned*)(ws + o); o += 4;

    // hole list reuses recs (dead after chunk-1 accum): capacity TOT u32 = 59.0 MB
    unsigned* holes = (unsigned*)recs;

    const int bin_blocks   = HB * (Hn / RG);   // 720
    const int strip_blocks = HB * (Hn / S);    // 1440

    for (int chunk = 0; chunk < 2; ++chunk) {
        const float* fchunk = flow + (size_t)chunk * HB * 2 * HW;
        float* ochunk = out + (size_t)chunk * HB * 2 * HW;
        unsigned long long* mchunk = mask + (size_t)chunk * (HB * HW / 64);

        hipMemsetAsync(bin_count, 0, (size_t)NBINC * 4, stream);
        count_k<<<bin_blocks, 1024, 0, stream>>>(fchunk, bin_count);
        scan_k<<<1, 1024, 0, stream>>>(bin_count, off, cur);
        emit_k<<<bin_blocks, 1024, 0, stream>>>(fchunk, cur, recs);
        accum_k<<<strip_blocks, 512, 0, stream>>>(off, recs, ochunk, mchunk);
    }

    hipMemsetAsync(hole_cnt, 0, 4, stream);

    const int tr_tiles = Bn * CW * WPR;                 // 3840 tiles
    transpose_k<<<tr_tiles / 4, 256, 0, stream>>>(mask, colmask);
    compact_k<<<NWORDS / 256, 256, 0, stream>>>(mask, holes, hole_cnt);
    fillc_k<<<1024, 256, 0, stream>>>(out, mask, colmask, holes, hole_cnt);
}